// Round 7
// baseline (480.115 us; speedup 1.0000x reference)
//
#include <hip/hip_runtime.h>
#include <math.h>

#define BS_TOK 16384   // B*S
#define DIM    2048    // D
#define NEXP   64      // E
#define DHID   1024    // D/2
#define GKS    4       // gate k-split
#define KSL    (DIM / GKS)

typedef __attribute__((ext_vector_type(8))) _Float16 f16x8;
typedef __attribute__((ext_vector_type(4))) float    f32x4;

#define GLOBAL_AS const __attribute__((address_space(1))) void*
#define LDS_AS    __attribute__((address_space(3))) void*
#define GLDS16(g, l) __builtin_amdgcn_global_load_lds((GLOBAL_AS)(g), (LDS_AS)(l), 16, 0, 0)

__device__ __forceinline__ float gelu_f(float x) {
  return 0.5f * x * (1.0f + erff(x * 0.70710678118654752440f));
}

// ================= prep: roles interleaved by bid%21 so LDS-bound gate blocks
// co-schedule with BW-bound LN blocks on every CU.
//   bid%21 == 0      -> gate   (256 blocks: 64 m-tiles x GKS=4)
//   bid%21 in 1..16  -> LN     (4096 blocks)
//   bid%21 in 17..20 -> W1cast (1024 blocks)
#define PREP_NB (21 * 256)

__global__ __launch_bounds__(256, 2) void prep_kernel(const float* __restrict__ X,
                                                      const float* __restrict__ Wg,
                                                      const float* __restrict__ gamma,
                                                      const float* __restrict__ beta,
                                                      const float* __restrict__ W1,
                                                      _Float16* __restrict__ H,
                                                      _Float16* __restrict__ W1h,
                                                      float* __restrict__ logitsP) {
  const int bid  = blockIdx.x;
  const int tid  = threadIdx.x;
  const int role = bid % 21;
  const int grp  = bid / 21;
  __shared__ float sX[16][264];   // gate staging [k][m], padded
  __shared__ float sW[16][68];    // gate staging [k][e], padded

  if (role == 0) {
    // ---- gate partials: logitsP[ks] = X[:, ks-slice] . Wg[:, ks-slice]^T ----
    // 256x64 tile, 8x8 micro (64 acc VGPRs; launch_bounds(256,2) -> no spill),
    // k-split 4. Per-logit k summation order identical to prior rounds.
    const int gi   = grp;            // 0..255
    const int m0   = (gi >> 2) * 256;
    const int ks   = gi & 3;
    const int k0   = ks * KSL;
    const int srow = tid >> 2;       // 0..63 staging row
    const int skq  = tid & 3;        // k-quad
    const int tr   = tid >> 3;       // 0..31, 8 tokens each
    const int tc   = tid & 7;        // 0..7, 8 experts each
    const float* xb = X  + (size_t)(m0 + srow) * DIM + k0 + skq * 4;
    const float* wb = Wg + (size_t)srow * DIM + k0 + skq * 4;
    float acc[8][8] = {};
    float4 rx[4], rw;
#pragma unroll
    for (int r = 0; r < 4; ++r) rx[r] = *(const float4*)(xb + (size_t)r * 64 * DIM);
    rw = *(const float4*)wb;
    for (int kt = 0; kt < KSL; kt += 16) {
      __syncthreads();
#pragma unroll
      for (int r = 0; r < 4; ++r) {
        sX[skq * 4 + 0][r * 64 + srow] = rx[r].x;
        sX[skq * 4 + 1][r * 64 + srow] = rx[r].y;
        sX[skq * 4 + 2][r * 64 + srow] = rx[r].z;
        sX[skq * 4 + 3][r * 64 + srow] = rx[r].w;
      }
      sW[skq * 4 + 0][srow] = rw.x;
      sW[skq * 4 + 1][srow] = rw.y;
      sW[skq * 4 + 2][srow] = rw.z;
      sW[skq * 4 + 3][srow] = rw.w;
      const int ktn = (kt + 16 < KSL) ? kt + 16 : 0;   // harmless reload on last iter
#pragma unroll
      for (int r = 0; r < 4; ++r) rx[r] = *(const float4*)(xb + (size_t)r * 64 * DIM + ktn);
      rw = *(const float4*)(wb + ktn);
      __syncthreads();
#pragma unroll
      for (int k = 0; k < 16; ++k) {
        float av[8], bv[8];
        *(float4*)(av)     = *(const float4*)&sX[k][tr * 8];
        *(float4*)(av + 4) = *(const float4*)&sX[k][tr * 8 + 4];
        *(float4*)(bv)     = *(const float4*)&sW[k][tc * 8];
        *(float4*)(bv + 4) = *(const float4*)&sW[k][tc * 8 + 4];
#pragma unroll
        for (int i = 0; i < 8; ++i)
#pragma unroll
          for (int j = 0; j < 8; ++j) acc[i][j] += av[i] * bv[j];
      }
    }
    float* op = logitsP + (size_t)ks * (BS_TOK * NEXP)
              + (size_t)(m0 + tr * 8) * NEXP + tc * 8;
#pragma unroll
    for (int i = 0; i < 8; ++i) {
      float4 o0, o1;
      o0.x = acc[i][0]; o0.y = acc[i][1]; o0.z = acc[i][2]; o0.w = acc[i][3];
      o1.x = acc[i][4]; o1.y = acc[i][5]; o1.z = acc[i][6]; o1.w = acc[i][7];
      *(float4*)(op + (size_t)i * NEXP)     = o0;
      *(float4*)(op + (size_t)i * NEXP + 4) = o1;
    }
  } else if (role <= 16) {
    // ---- LayerNorm -> f16 H : one wave per token, no LDS, no barriers ----
    const int lid  = grp * 16 + (role - 1);   // 0..4095
    const int w    = tid >> 6, lane = tid & 63;
    const int t    = lid * 4 + w;
    const float* xr = X + (size_t)t * DIM;
    float4 xv[8];
#pragma unroll
    for (int j = 0; j < 4; ++j) {
      const int c0 = (j * 64 + lane) * 8;
      xv[j * 2]     = *(const float4*)(xr + c0);
      xv[j * 2 + 1] = *(const float4*)(xr + c0 + 4);
    }
    float s = 0.f, q = 0.f;
#pragma unroll
    for (int j = 0; j < 8; ++j) {
      s += (xv[j].x + xv[j].y) + (xv[j].z + xv[j].w);
      q += (xv[j].x * xv[j].x + xv[j].y * xv[j].y) + (xv[j].z * xv[j].z + xv[j].w * xv[j].w);
    }
#pragma unroll
    for (int off = 32; off > 0; off >>= 1) {
      s += __shfl_xor(s, off);
      q += __shfl_xor(q, off);
    }
    const float mu  = s * (1.0f / DIM);
    const float var = q * (1.0f / DIM) - mu * mu;
    const float rs  = rsqrtf(var + 1e-5f);
#pragma unroll
    for (int j = 0; j < 4; ++j) {
      const int c0 = (j * 64 + lane) * 8;
      const float4 g0 = *(const float4*)(gamma + c0);
      const float4 g1 = *(const float4*)(gamma + c0 + 4);
      const float4 b0 = *(const float4*)(beta + c0);
      const float4 b1 = *(const float4*)(beta + c0 + 4);
      const float4 a = xv[j * 2], b = xv[j * 2 + 1];
      f16x8 h;
      h[0] = (_Float16)((a.x - mu) * rs * g0.x + b0.x);
      h[1] = (_Float16)((a.y - mu) * rs * g0.y + b0.y);
      h[2] = (_Float16)((a.z - mu) * rs * g0.z + b0.z);
      h[3] = (_Float16)((a.w - mu) * rs * g0.w + b0.w);
      h[4] = (_Float16)((b.x - mu) * rs * g1.x + b1.x);
      h[5] = (_Float16)((b.y - mu) * rs * g1.y + b1.y);
      h[6] = (_Float16)((b.z - mu) * rs * g1.z + b1.z);
      h[7] = (_Float16)((b.w - mu) * rs * g1.w + b1.w);
      *(f16x8*)(H + (size_t)t * DIM + c0) = h;
    }
  } else {
    // ---- W1 fp32 -> f16 ----
    const int cid = grp * 4 + (role - 17);    // 0..1023
    const int i   = (cid * 256 + tid) * 8;
    const float4 a = *(const float4*)(W1 + i);
    const float4 b = *(const float4*)(W1 + i + 4);
    f16x8 o;
    o[0] = (_Float16)a.x; o[1] = (_Float16)a.y; o[2] = (_Float16)a.z; o[3] = (_Float16)a.w;
    o[4] = (_Float16)b.x; o[5] = (_Float16)b.y; o[6] = (_Float16)b.z; o[7] = (_Float16)b.w;
    *(f16x8*)(W1h + i) = o;
  }
}

// ------- predictor GEMM: H1 = gelu(H . W1^T); z[t] += sum_n H1*W2 (fused) -------
// XCD-swizzled grid; conflict-free MFMA-order LDS layout (frag read == staging
// dest pattern, stride-1 per wave); 2-barrier K-loop with BK=64 (two 32-k
// sub-tiles per barrier -> batched vmcnt drain amortized over 32 MFMAs).
__global__ __launch_bounds__(256, 3) void g2_kernel(const _Float16* __restrict__ H,
                                                    const _Float16* __restrict__ W1h,
                                                    const float* __restrict__ W2,
                                                    float* __restrict__ diffz) {
  __shared__ __align__(16) _Float16 sA[8192];   // 2 sub-tiles x 128 rows x 32 k
  __shared__ __align__(16) _Float16 sB[8192];
  const int bid = blockIdx.x;
  const int c   = bid & 7;
  const int j   = bid >> 3;
  const int m0  = (c * 16 + (j >> 3)) * 128;
  const int n0  = (j & 7) * 128;
  const int tid  = threadIdx.x;
  const int w    = tid >> 6, lane = tid & 63;
  const int wr   = w >> 1,  wc   = w & 1;
  const int col  = lane & 15, quad = lane >> 4;
  const int r    = lane & 15, q = lane >> 4;     // staging row-in-group / k-octet
  const int gA   = w * 2;                         // this wave stages groups gA, gA+1
  const _Float16* srcA0 = H   + (size_t)(m0 + gA * 16 + r) * DIM + q * 8;
  const _Float16* srcA1 = srcA0 + (size_t)16 * DIM;
  const _Float16* srcB0 = W1h + (size_t)(n0 + gA * 16 + r) * DIM + q * 8;
  const _Float16* srcB1 = srcB0 + (size_t)16 * DIM;
  const int dOff = gA * 512 + lane * 8;
  f32x4 acc[4][4] = {};
  for (int kt = 0; kt < DIM; kt += 64) {
    __syncthreads();
    GLDS16(srcA0 + kt,      sA + dOff);
    GLDS16(srcA1 + kt,      sA + dOff + 512);
    GLDS16(srcA0 + kt + 32, sA + 4096 + dOff);
    GLDS16(srcA1 + kt + 32, sA + 4096 + dOff + 512);
    GLDS16(srcB0 + kt,      sB + dOff);
    GLDS16(srcB1 + kt,      sB + dOff + 512);
    GLDS16(srcB0 + kt + 32, sB + 4096 + dOff);
    GLDS16(srcB1 + kt + 32, sB + 4096 + dOff + 512);
    __syncthreads();
#pragma unroll
    for (int s = 0; s < 2; ++s) {
      const int base = s * 4096;
      f16x8 af[4], bf[4];
#pragma unroll
      for (int mi = 0; mi < 4; ++mi)
        af[mi] = *(const f16x8*)(sA + base + (wr * 4 + mi) * 512 + lane * 8);
#pragma unroll
      for (int ni = 0; ni < 4; ++ni)
        bf[ni] = *(const f16x8*)(sB + base + (wc * 4 + ni) * 512 + lane * 8);
#pragma unroll
      for (int mi = 0; mi < 4; ++mi)
#pragma unroll
        for (int ni = 0; ni < 4; ++ni)
          acc[mi][ni] = __builtin_amdgcn_mfma_f32_16x16x32_f16(af[mi], bf[ni], acc[mi][ni], 0, 0, 0);
    }
  }
  // epilogue: gelu -> * W2 -> reduce over the 128 n-cols this block owns
  float w2v[4];
#pragma unroll
  for (int ni = 0; ni < 4; ++ni) w2v[ni] = W2[n0 + wc * 64 + ni * 16 + col];
#pragma unroll
  for (int mi = 0; mi < 4; ++mi) {
#pragma unroll
    for (int reg = 0; reg < 4; ++reg) {
      float v = 0.f;
#pragma unroll
      for (int ni = 0; ni < 4; ++ni) v += gelu_f(acc[mi][ni][reg]) * w2v[ni];
      v += __shfl_xor(v, 1);
      v += __shfl_xor(v, 2);
      v += __shfl_xor(v, 4);
      v += __shfl_xor(v, 8);
      if (col == 0)
        atomicAdd(diffz + m0 + wr * 64 + mi * 16 + quad * 4 + reg, v);
    }
  }
}

// ---------------- per-token finalize: one wave per token, 32 tokens/block ----------------
__global__ __launch_bounds__(256) void finalize_kernel(const float* __restrict__ logitsP,
                                                       const float* __restrict__ diffz,
                                                       float* __restrict__ out_idx,
                                                       float* __restrict__ out_scores,
                                                       float* __restrict__ out_probs,
                                                       float* __restrict__ out_imp,
                                                       float* __restrict__ out_load) {
  const int tid  = threadIdx.x;
  const int w    = tid >> 6, lane = tid & 63;
  const size_t PS = (size_t)BS_TOK * NEXP;
  float acc_imp = 0.f, acc_load = 0.f;
  for (int it = 0; it < 8; ++it) {
    const int t    = blockIdx.x * 32 + it * 4 + w;
    const float* lp = logitsP + (size_t)t * NEXP + lane;
    const float L  = ((lp[0] + lp[PS]) + lp[2 * PS]) + lp[3 * PS];
    const float z  = diffz[t];
    const float d  = 1.0f / (1.0f + expf(-z));
    const float l  = L / (1.0f + d);          // TEMP == 1
    // fused top-2 tournament butterfly; key = (value desc, index asc).
    float v1 = l; int i1 = lane;
    float v2 = -INFINITY; int i2 = 0;
#pragma unroll
    for (int off = 32; off > 0; off >>= 1) {
      const float ov1 = __shfl_xor(v1, off); const int oi1 = __shfl_xor(i1, off);
      const float ov2 = __shfl_xor(v2, off); const int oi2 = __shfl_xor(i2, off);
      const bool bwin = (ov1 > v1) || (ov1 == v1 && oi1 < i1);
      const float w1 = bwin ? ov1 : v1; const int wi1 = bwin ? oi1 : i1;
      const float l1 = bwin ? v1 : ov1; const int li1 = bwin ? i1 : oi1;
      const float c2 = bwin ? ov2 : v2; const int ci2 = bwin ? oi2 : i2;
      const bool s2w = (c2 > l1) || (c2 == l1 && ci2 < li1);
      v2 = s2w ? c2 : l1; i2 = s2w ? ci2 : li1;
      v1 = w1; i1 = wi1;
    }
    // softmax using v1 as max
    float p = expf(l - v1);
    float s = p;
#pragma unroll
    for (int off = 32; off > 0; off >>= 1) s += __shfl_xor(s, off);
    p /= s;
    const float p1 = __shfl(p, i1);
    const float p2 = __shfl(p, i2);
    const float s1 = (1.0f - p1) + p1;        // straight-through, fp32-faithful
    const float s2 = (1.0f - p2) + p2;
    const float den = fmaxf(s1 + s2, 1e-9f);
    if (lane == 0) {
      out_idx[t * 2]        = (float)i1;
      out_idx[t * 2 + 1]    = (float)i2;
      out_scores[t * 2]     = s1 / den;
      out_scores[t * 2 + 1] = s2 / den;
    }
    out_probs[(size_t)t * NEXP + lane] = p;
    acc_imp  += p;
    acc_load += (lane == i1 || lane == i2) ? 1.0f : 0.0f;
  }
  __shared__ float s_imp[256];
  __shared__ float s_hard[256];
  s_imp[tid]  = acc_imp;
  s_hard[tid] = acc_load;
  __syncthreads();
  if (tid < 64) {
    const float inv = 1.0f / (float)BS_TOK;
    const float si = s_imp[tid] + s_imp[64 + tid] + s_imp[128 + tid] + s_imp[192 + tid];
    const float sl = s_hard[tid] + s_hard[64 + tid] + s_hard[128 + tid] + s_hard[192 + tid];
    atomicAdd(out_imp + tid, si * inv);
    atomicAdd(out_load + tid, sl * inv);
  }
}

extern "C" void kernel_launch(void* const* d_in, const int* in_sizes, int n_in,
                              void* d_out, int out_size, void* d_ws, size_t ws_size,
                              hipStream_t stream) {
  (void)in_sizes; (void)n_in; (void)out_size; (void)ws_size;
  const float* X     = (const float*)d_in[0];
  const float* Wg    = (const float*)d_in[1];
  const float* gamma = (const float*)d_in[2];
  const float* beta  = (const float*)d_in[3];
  const float* W1    = (const float*)d_in[4];
  const float* W2    = (const float*)d_in[5];
  float* out = (float*)d_out;

  char* ws = (char*)d_ws;
  _Float16* H       = (_Float16*)(ws);                    // 64 MB
  _Float16* W1h     = (_Float16*)(ws + 67108864ull);      // 4 MB
  float*    logitsP = (float*)  (ws + 71303168ull);       // 16 MB (4 k-split partials)
  float*    diffz   = (float*)  (ws + 88080384ull);       // 64 KB

  // out layout (all float32): idx[32768] | scores[32768] | probs[1048576] | imp[64] | load[64]
  float* out_idx    = out;
  float* out_scores = out + 32768;
  float* out_probs  = out + 65536;
  float* out_imp    = out + 1114112;
  float* out_load   = out + 1114176;

  hipMemsetAsync(diffz, 0, 65536ull, stream);
  hipMemsetAsync(out_imp, 0, 512ull, stream);
  prep_kernel<<<PREP_NB, 256, 0, stream>>>(X, Wg, gamma, beta, W1, H, W1h, logitsP);
  g2_kernel<<<(DHID / 128) * (BS_TOK / 128), 256, 0, stream>>>(H, W1h, W2, diffz);
  finalize_kernel<<<BS_TOK / 32, 256, 0, stream>>>(logitsP, diffz, out_idx, out_scores,
                                                   out_probs, out_imp, out_load);
}